// Round 3
// baseline (208.300 us; speedup 1.0000x reference)
//
#include <hip/hip_runtime.h>

typedef float f2 __attribute__((ext_vector_type(2)));
typedef float f4v __attribute__((ext_vector_type(4)));

// Dims fixed by setup_inputs: flow [4,2,256,256] f32, spike [4,64,256,256] f32
constexpr int B = 4, C = 64, H = 256, W = 256;
constexpr int HW = H * W;
constexpr long long N_TOT = (long long)C * HW;   // 4,194,304

constexpr int TW = 16, TH = 8;      // output part dims (16 wide x 8 tall)
constexpr int INW = 18, INH = 10;   // core region: part + 1 ring (x in [-1,16], y in [-1,8])
constexpr int INA = INW * INH;      // 180
constexpr int OVW = 19, OVH = 10;   // overflow plane (cols 1..16 valid, 17/18 dump; rows 1..8 valid, 9 dump)
constexpr int OVA = OVW * OVH;      // 190
constexpr int NPART = 512;          // 16 cols x 32 rows of 16x8 parts
constexpr int NBLK = NPART * 8;     // 4096 blocks

// ---------------------------------------------------------------------------
// Round-3: parallelism/balance edition of the hybrid gather/scatter.
// Round-2 analysis: VALU floor ~32us but avg resident waves ~5.8/CU (Occ 18%)
// because grid was only 8 blocks/CU with j-dependent cost dispatched slow-last.
// Changes (total VALU work unchanged):
//  - 16x16 tile -> two 16x8 parts; 8 channels -> 2 thread-halves (t01 / t23).
//    Grid 2048 -> 4096, per-block work ~1/4, LDS 24KB -> ~13.4KB,
//    per-thread state ~1/2 (acc 4 floats, 4 spike ch/cell).
//  - Dispatch balance: j = 7 - ((bid ^ (bid>>3)) & 7) interleaves chunk cost
//    across consecutive bids AND XCDs (bid&7 alone would pin j per XCD).
//  - Hybrid partition unchanged (exact): non-event pairs via fixed 3x3 gather
//    with med3 clamp-tents; rare far-reaching pairs (es*s>=1, EXEC-sparse)
//    via ds_add_f32 into small LDS overflow planes. Dense LDS atomics remain
//    banned (round-1: 208 cyc/wave-instr).
// ---------------------------------------------------------------------------
__global__ __launch_bounds__(256, 6) void fused_kernel(
    const float* __restrict__ flow,
    const float* __restrict__ spike,
    double* __restrict__ partials) {
  __shared__ __align__(16) f4v spk0[INA];   // half0: {neg0,pos0,neg1,pos1} per cell
  __shared__ __align__(16) f4v spk1[INA];   // half1: {neg2,pos2,neg3,pos3}
  __shared__ f2 uv[INA];                    // {u,v} per core cell
  __shared__ __align__(16) float ovf[8 * OVA];  // overflow accum, 8 channels
  __shared__ double red[8];

  const int bid = blockIdx.x;
  const int part = bid >> 3;
  const int j = 7 - ((bid ^ (bid >> 3)) & 7);   // cost-interleaved, XCD-balanced
  const int tx0 = (part & 15) * TW;
  const int ty0 = (part >> 4) * TH;
  const int tid = threadIdx.x;
  const int l = tid & 127;            // pixel lane within half
  const int half = tid >> 7;          // 0: pairs t=0,1   1: pairs t=2,3
  const int tb = 2 * half;
  const int qx = l & 15, qy = l >> 4;
  const int wave = tid >> 6;

  // zero overflow planes (8*190 = 1520 floats)
  {
    f4v z = {0.f, 0.f, 0.f, 0.f};
    f4v* ov4 = (f4v*)ovf;
    for (int i = tid; i < (8 * OVA) / 4; i += 256) ov4[i] = z;
  }

  f2 smv[2];                          // {-s, +s} for this half's two pairs
  float sm[2];
#pragma unroll
  for (int tt = 0; tt < 2; ++tt) {
    float s = ((float)(4 * j + tb + tt) + 0.5f) * (1.0f / 64.0f);
    sm[tt] = s;
    smv[tt] = f2{-s, s};
  }
  const int cn = 31 - 4 * j - tb;     // this half's first neg channel (descending)
  const int cp = 32 + 4 * j + tb;     // first pos channel (ascending)
  const int Rj = (j >> 1) + 1;        // {1,1,2,2,3,3,4,4}
  const int SWj = TW + 2 * Rj;
  const int SAj = SWj * (TH + 2 * Rj);  // <= 384

  // Batch-invariant per-cell staging geometry (cells pos = l + 128k)
  bool c_act[3], c_val[3], c_inn[3];
  int c_gp[3], c_ip[3];
  float c_px[3], c_py[3];
#pragma unroll
  for (int k = 0; k < 3; ++k) {
    int pos = l + 128 * k;
    bool act = pos < SAj;
    int row = act ? pos / SWj : 0;    // runtime div, 3x once per kernel
    int col = pos - row * SWj;
    int relx = col - Rj, rely = row - Rj;   // [-Rj, 15+Rj] x [-Rj, 7+Rj]
    int gy = ty0 + rely, gx = tx0 + relx;
    c_act[k] = act;
    c_val[k] = act & ((unsigned)gy < (unsigned)H) & ((unsigned)gx < (unsigned)W);
    c_gp[k] = gy * W + gx;
    c_inn[k] = act & (relx >= -1) & (relx <= TW) & (rely >= -1) & (rely <= TH);
    c_ip[k] = (rely + 1) * INW + (relx + 1);
    c_px[k] = (float)relx;
    c_py[k] = (float)rely;
  }

  float p_u[3], p_v[3];
  float4 p_s[3];                      // {n0, p0, n1, p1} for this half

  auto prefetch = [&](int bb) {
    const float* fu = flow + (size_t)bb * 2 * HW;
    const float* fv = fu + HW;
    const float* spb = spike + (size_t)bb * C * HW;
#pragma unroll
    for (int k = 0; k < 3; ++k) {
      float u = 0.f, v = 0.f;
      float4 s4 = {0.f, 0.f, 0.f, 0.f};
      if (c_val[k]) {
        int gp = c_gp[k];
        u = fu[gp];
        v = fv[gp];
        s4.x = spb[(size_t)cn * HW + gp];
        s4.y = spb[(size_t)cp * HW + gp];
        s4.z = spb[(size_t)(cn - 1) * HW + gp];
        s4.w = spb[(size_t)(cp + 1) * HW + gp];
      }
      p_u[k] = u; p_v[k] = v; p_s[k] = s4;
    }
  };

  prefetch(0);
  __syncthreads();                    // ovf zero-init visible before any event

  const int qip = (qy + 1) * INW + (qx + 1);
  const f4v* spkH = half ? spk1 : spk0;
  f2 acc2[2];
  acc2[0] = f2{0.f, 0.f};
  acc2[1] = f2{0.f, 0.f};

  for (int bb = 0; bb < B; ++bb) {
    // ---- stage core cells to LDS + sparse event scatter ----
#pragma unroll
    for (int k = 0; k < 3; ++k) {
      if (!c_act[k]) continue;
      float u = p_u[k], v = p_v[k];
      float4 s4 = p_s[k];
      float es = fmaxf(fabsf(u), fabsf(v));
      bool ev0 = es * sm[0] >= 1.0f;
      bool ev1 = es * sm[1] >= 1.0f;  // superset of ev0 (sm increasing)
      if (c_inn[k]) {
        int ip = c_ip[k];
        if (half == 0) uv[ip] = f2{u, v};
        f4v* dst = half ? spk1 : spk0;
        dst[ip] = f4v{ev0 ? 0.f : s4.x, ev0 ? 0.f : s4.y,
                      ev1 ? 0.f : s4.z, ev1 ? 0.f : s4.w};
      }
      if (__any(ev1)) {
        const f2 u2 = f2{u, u}, v2 = f2{v, v};
        const f2 px2 = f2{c_px[k], c_px[k]}, py2 = f2{c_py[k], c_py[k]};
        const float nv[2] = {s4.x, s4.z};
        const float pv[2] = {s4.y, s4.w};
#pragma unroll
        for (int tt = 0; tt < 2; ++tt) {
          bool ev = es * sm[tt] >= 1.0f;
          if (ev) {                   // EXEC-sparse; s_cbranch_execz skips
            f2 xn = __builtin_elementwise_fma(u2, smv[tt], px2);
            f2 yn = __builtin_elementwise_fma(v2, smv[tt], py2);
#pragma unroll
            for (int h = 0; h < 2; ++h) {
              float x = xn[h], y = yn[h];
              float val = h ? pv[tt] : nv[tt];
              float fx = floorf(x), fy = floorf(y);
              float f = x - fx, g = y - fy;
              int X0 = (int)fx, Y0 = (int)fy;
              // route out-of-part corners to dump row/cols
              int ix0 = ((unsigned)X0 < (unsigned)TW) ? X0 + 1 : 17;
              int ix1 = ((unsigned)(X0 + 1) < (unsigned)TW) ? X0 + 2 : 18;
              int iy0 = ((unsigned)Y0 < (unsigned)TH) ? Y0 + 1 : 9;
              int iy1 = ((unsigned)(Y0 + 1) < (unsigned)TH) ? Y0 + 2 : 9;
              float* pl = &ovf[(2 * (tb + tt) + h) * OVA];
              float w1 = f * val, w0 = val - w1;
              float g1 = g, g0 = 1.0f - g;
              atomicAdd(pl + iy0 * OVW + ix0, w0 * g0);
              atomicAdd(pl + iy0 * OVW + ix1, w1 * g0);
              atomicAdd(pl + iy1 * OVW + ix0, w0 * g1);
              atomicAdd(pl + iy1 * OVW + ix1, w1 * g1);
            }
          }
        }
      }
    }
    __syncthreads();                  // staging visible
    if (bb + 1 < B) prefetch(bb + 1); // overlap HBM latency with gather

    // ---- fixed 3x3 core gather (this half's two pairs) ----
#pragma unroll
    for (int dy = -1; dy <= 1; ++dy) {
#pragma unroll
      for (int dx = -1; dx <= 1; ++dx) {
        const int ip = qip + dy * INW + dx;
        const f2 u2v = uv[ip];
        const f4v A = spkH[ip];
        const f2 ux = f2{u2v.x, u2v.x};
        const f2 vy = f2{u2v.y, u2v.y};
        const f2 fdx2 = (float)dx;
        const f2 fdy2 = (float)dy;
        const f2 vals[2] = {f2{A[0], A[1]}, f2{A[2], A[3]}};
#pragma unroll
        for (int tt = 0; tt < 2; ++tt) {
          f2 ax = __builtin_elementwise_fma(ux, smv[tt], fdx2);
          f2 ay = __builtin_elementwise_fma(vy, smv[tt], fdy2);
          f2 tx, ty;
          tx[0] = __builtin_amdgcn_fmed3f(1.0f - fabsf(ax[0]), 0.f, 1.f);
          tx[1] = __builtin_amdgcn_fmed3f(1.0f - fabsf(ax[1]), 0.f, 1.f);
          ty[0] = __builtin_amdgcn_fmed3f(1.0f - fabsf(ay[0]), 0.f, 1.f);
          ty[1] = __builtin_amdgcn_fmed3f(1.0f - fabsf(ay[1]), 0.f, 1.f);
          acc2[tt] = __builtin_elementwise_fma(tx * ty, vals[tt], acc2[tt]);
        }
      }
    }
    __syncthreads();                  // LDS reused by next batch
  }

  // add overflow (event) contributions for this thread's pixel/channels
  const int oip = (qy + 1) * OVW + (qx + 1);
#pragma unroll
  for (int tt = 0; tt < 2; ++tt) {
    acc2[tt] += f2{ovf[(2 * (tb + tt)) * OVA + oip],
                   ovf[(2 * (tb + tt) + 1) * OVA + oip]};
  }

  // variance partials over this thread's 4 output cells
  double ls = 0.0, lq = 0.0;
#pragma unroll
  for (int tt = 0; tt < 2; ++tt) {
    double a = (double)acc2[tt].x, b2 = (double)acc2[tt].y;
    ls += a + b2;
    lq += a * a + b2 * b2;
  }
  for (int off = 32; off > 0; off >>= 1) {
    ls += __shfl_down(ls, off, 64);
    lq += __shfl_down(lq, off, 64);
  }
  if ((tid & 63) == 0) { red[wave * 2] = ls; red[wave * 2 + 1] = lq; }
  __syncthreads();
  if (tid == 0) {
    partials[2 * bid] = red[0] + red[2] + red[4] + red[6];
    partials[2 * bid + 1] = red[1] + red[3] + red[5] + red[7];
  }
}

// ---------------------------------------------------------------------------
// Finalize: reduce NBLK partial pairs, loss = -(sumsq - sum^2/N)/(N-1)
// ---------------------------------------------------------------------------
__global__ __launch_bounds__(256) void finalize_kernel(
    const double* __restrict__ partials, float* __restrict__ out) {
  double s = 0.0, q = 0.0;
  for (int i = threadIdx.x; i < NBLK; i += 256) {
    s += partials[2 * i];
    q += partials[2 * i + 1];
  }
  for (int off = 32; off > 0; off >>= 1) {
    s += __shfl_down(s, off, 64);
    q += __shfl_down(q, off, 64);
  }
  __shared__ double ss[4], qq[4];
  int lane = threadIdx.x & 63;
  int wave = threadIdx.x >> 6;
  if (lane == 0) { ss[wave] = s; qq[wave] = q; }
  __syncthreads();
  if (threadIdx.x == 0) {
    double sum = ss[0] + ss[1] + ss[2] + ss[3];
    double sq = qq[0] + qq[1] + qq[2] + qq[3];
    double n = (double)N_TOT;
    double var = (sq - sum * sum / n) / (n - 1.0);
    out[0] = (float)(-var);
  }
}

extern "C" void kernel_launch(void* const* d_in, const int* in_sizes, int n_in,
                              void* d_out, int out_size, void* d_ws, size_t ws_size,
                              hipStream_t stream) {
  const float* flow = (const float*)d_in[0];
  const float* spike = (const float*)d_in[1];
  float* out = (float*)d_out;
  double* partials = (double*)d_ws;   // 2*NBLK doubles, fully written each call

  fused_kernel<<<dim3(NBLK), dim3(256), 0, stream>>>(flow, spike, partials);
  finalize_kernel<<<1, dim3(256), 0, stream>>>(partials, out);
}

// Round 4
// 158.080 us; speedup vs baseline: 1.3177x; 1.3177x over previous
//
#include <hip/hip_runtime.h>

typedef float f2 __attribute__((ext_vector_type(2)));
typedef float f4v __attribute__((ext_vector_type(4)));

// Dims fixed by setup_inputs: flow [4,2,256,256] f32, spike [4,64,256,256] f32
constexpr int B = 4, C = 64, H = 256, W = 256;
constexpr int HW = H * W;
constexpr long long N_TOT = (long long)C * HW;   // 4,194,304

constexpr int TW = 16, TH = 8;      // output part dims (16 wide x 8 tall)
constexpr int INW = 18, INH = 10;   // core region: part + 1 ring (x in [-1,16], y in [-1,8])
constexpr int INA = INW * INH;      // 180
constexpr int OVW = 19, OVH = 10;   // overflow plane (cols 1..16 valid, 17/18 dump; rows 1..8 valid, 9 dump)
constexpr int OVA = OVW * OVH;      // 190
constexpr int NPART = 512;          // 16 cols x 32 rows of 16x8 parts
constexpr int NBLK = NPART * 8;     // 4096 blocks

// ---------------------------------------------------------------------------
// Round-4: Round-3 structure, spill-free.
// Round-3 post-mortem: __launch_bounds__(256,6) forced the <=64-VGPR HW tier
// (tiers step at 64/128/256), the allocator spilled the prefetch state to
// scratch -> 123MB HBM writes + ~100MB reloads, dur 73->128us. Fix:
//  - plain __launch_bounds__(256); no min-waves clause.
//  - register thrift: per-cell geometry packed into one int c_rc=(row<<8)|col
//    (W=256 so gp = sbase + c_rc exactly); ip/px/py recomputed per batch
//    (~6 VALU/cell/batch) instead of 9 persistent VGPRs.
// Structure kept from Round-3 (it worked: Occ 18->50%):
//  - 16x8 parts x 2 channel-half thread groups; grid 4096, LDS ~13.5KB.
//  - j = 7-((bid^(bid>>3))&7): cost-interleaved across bids AND XCDs.
//  - Exact hybrid: non-event pairs via fixed 3x3 med3-tent gather; rare
//    far-reaching pairs (es*s>=1, EXEC-sparse) via ds_add_f32 overflow planes.
//    Dense LDS atomics banned (round-1: 208 cyc/wave-instr).
// ---------------------------------------------------------------------------
__global__ __launch_bounds__(256) void fused_kernel(
    const float* __restrict__ flow,
    const float* __restrict__ spike,
    double* __restrict__ partials) {
  __shared__ __align__(16) f4v spk0[INA];   // half0: {neg0,pos0,neg1,pos1} per cell
  __shared__ __align__(16) f4v spk1[INA];   // half1: {neg2,pos2,neg3,pos3}
  __shared__ f2 uv[INA];                    // {u,v} per core cell
  __shared__ __align__(16) float ovf[8 * OVA];  // overflow accum, 8 channels
  __shared__ double red[8];

  const int bid = blockIdx.x;
  const int part = bid >> 3;
  const int j = 7 - ((bid ^ (bid >> 3)) & 7);   // cost-interleaved, XCD-balanced
  const int tx0 = (part & 15) * TW;
  const int ty0 = (part >> 4) * TH;
  const int tid = threadIdx.x;
  const int l = tid & 127;            // pixel lane within half
  const int half = tid >> 7;          // 0: pairs t=0,1   1: pairs t=2,3
  const int tb = 2 * half;
  const int qx = l & 15, qy = l >> 4;
  const int wave = tid >> 6;

  // zero overflow planes (8*190 = 1520 floats)
  {
    f4v z = {0.f, 0.f, 0.f, 0.f};
    f4v* ov4 = (f4v*)ovf;
    for (int i = tid; i < (8 * OVA) / 4; i += 256) ov4[i] = z;
  }

  f2 smv[2];                          // {-s, +s} for this half's two pairs
  float sm[2];
#pragma unroll
  for (int tt = 0; tt < 2; ++tt) {
    float s = ((float)(4 * j + tb + tt) + 0.5f) * (1.0f / 64.0f);
    sm[tt] = s;
    smv[tt] = f2{-s, s};
  }
  const int cn = 31 - 4 * j - tb;     // this half's first neg channel (descending)
  const int cp = 32 + 4 * j + tb;     // first pos channel (ascending)
  const int Rj = (j >> 1) + 1;        // {1,1,2,2,3,3,4,4}
  const int SWj = TW + 2 * Rj;
  const int SAj = SWj * (TH + 2 * Rj);  // <= 384

  // scalar geometry bases
  const int sbg = (ty0 - Rj) * W + (tx0 - Rj);   // gp = sbg + (row<<8|col)
  const int ipc = (1 - Rj) * (INW + 1);          // ip = row*INW + col + ipc
  const float pxc = (float)(-Rj), pyc = (float)(-Rj);

  // Batch-invariant per-cell staging geometry (cells pos = l + 128k), packed
  bool c_act[3], c_val[3], c_inn[3];
  int c_rc[3];                         // (row<<8) | col
#pragma unroll
  for (int k = 0; k < 3; ++k) {
    int pos = l + 128 * k;
    bool act = pos < SAj;
    int row = act ? pos / SWj : 0;    // runtime div, 3x once per kernel
    int col = pos - row * SWj;
    int relx = col - Rj, rely = row - Rj;   // [-Rj, 15+Rj] x [-Rj, 7+Rj]
    int gy = ty0 + rely, gx = tx0 + relx;
    c_act[k] = act;
    c_val[k] = act & ((unsigned)gy < (unsigned)H) & ((unsigned)gx < (unsigned)W);
    c_inn[k] = act & (relx >= -1) & (relx <= TW) & (rely >= -1) & (rely <= TH);
    c_rc[k] = (row << 8) | col;
  }

  float p_u[3], p_v[3];
  float4 p_s[3];                      // {n0, p0, n1, p1} for this half

  auto prefetch = [&](int bb) {
    const float* fu = flow + (size_t)bb * 2 * HW;
    const float* fv = fu + HW;
    const float* spb = spike + (size_t)bb * C * HW;
#pragma unroll
    for (int k = 0; k < 3; ++k) {
      float u = 0.f, v = 0.f;
      float4 s4 = {0.f, 0.f, 0.f, 0.f};
      if (c_val[k]) {
        int gp = sbg + c_rc[k];
        u = fu[gp];
        v = fv[gp];
        s4.x = spb[(size_t)cn * HW + gp];
        s4.y = spb[(size_t)cp * HW + gp];
        s4.z = spb[(size_t)(cn - 1) * HW + gp];
        s4.w = spb[(size_t)(cp + 1) * HW + gp];
      }
      p_u[k] = u; p_v[k] = v; p_s[k] = s4;
    }
  };

  prefetch(0);
  __syncthreads();                    // ovf zero-init visible before any event

  const int qip = (qy + 1) * INW + (qx + 1);
  const f4v* spkH = half ? spk1 : spk0;
  f2 acc2[2];
  acc2[0] = f2{0.f, 0.f};
  acc2[1] = f2{0.f, 0.f};

  for (int bb = 0; bb < B; ++bb) {
    // ---- stage core cells to LDS + sparse event scatter ----
#pragma unroll
    for (int k = 0; k < 3; ++k) {
      if (!c_act[k]) continue;
      int row = c_rc[k] >> 8, col = c_rc[k] & 255;
      float u = p_u[k], v = p_v[k];
      float4 s4 = p_s[k];
      float es = fmaxf(fabsf(u), fabsf(v));
      bool ev0 = es * sm[0] >= 1.0f;
      bool ev1 = es * sm[1] >= 1.0f;  // superset of ev0 (sm increasing)
      if (c_inn[k]) {
        int ip = row * INW + col + ipc;
        if (half == 0) uv[ip] = f2{u, v};
        f4v* dst = half ? spk1 : spk0;
        dst[ip] = f4v{ev0 ? 0.f : s4.x, ev0 ? 0.f : s4.y,
                      ev1 ? 0.f : s4.z, ev1 ? 0.f : s4.w};
      }
      if (__any(ev1)) {
        float px = (float)col + pxc, py = (float)row + pyc;
        const f2 u2 = f2{u, u}, v2 = f2{v, v};
        const f2 px2 = f2{px, px}, py2 = f2{py, py};
        const float nv[2] = {s4.x, s4.z};
        const float pv[2] = {s4.y, s4.w};
#pragma unroll
        for (int tt = 0; tt < 2; ++tt) {
          bool ev = es * sm[tt] >= 1.0f;
          if (ev) {                   // EXEC-sparse; s_cbranch_execz skips
            f2 xn = __builtin_elementwise_fma(u2, smv[tt], px2);
            f2 yn = __builtin_elementwise_fma(v2, smv[tt], py2);
#pragma unroll
            for (int h = 0; h < 2; ++h) {
              float x = xn[h], y = yn[h];
              float val = h ? pv[tt] : nv[tt];
              float fx = floorf(x), fy = floorf(y);
              float f = x - fx, g = y - fy;
              int X0 = (int)fx, Y0 = (int)fy;
              // route out-of-part corners to dump row/cols
              int ix0 = ((unsigned)X0 < (unsigned)TW) ? X0 + 1 : 17;
              int ix1 = ((unsigned)(X0 + 1) < (unsigned)TW) ? X0 + 2 : 18;
              int iy0 = ((unsigned)Y0 < (unsigned)TH) ? Y0 + 1 : 9;
              int iy1 = ((unsigned)(Y0 + 1) < (unsigned)TH) ? Y0 + 2 : 9;
              float* pl = &ovf[(2 * (tb + tt) + h) * OVA];
              float w1 = f * val, w0 = val - w1;
              float g1 = g, g0 = 1.0f - g;
              atomicAdd(pl + iy0 * OVW + ix0, w0 * g0);
              atomicAdd(pl + iy0 * OVW + ix1, w1 * g0);
              atomicAdd(pl + iy1 * OVW + ix0, w0 * g1);
              atomicAdd(pl + iy1 * OVW + ix1, w1 * g1);
            }
          }
        }
      }
    }
    __syncthreads();                  // staging visible
    if (bb + 1 < B) prefetch(bb + 1); // overlap HBM latency with gather

    // ---- fixed 3x3 core gather (this half's two pairs) ----
#pragma unroll
    for (int dy = -1; dy <= 1; ++dy) {
#pragma unroll
      for (int dx = -1; dx <= 1; ++dx) {
        const int ip = qip + dy * INW + dx;
        const f2 u2v = uv[ip];
        const f4v A = spkH[ip];
        const f2 ux = f2{u2v.x, u2v.x};
        const f2 vy = f2{u2v.y, u2v.y};
        const f2 fdx2 = (float)dx;
        const f2 fdy2 = (float)dy;
        const f2 vals[2] = {f2{A[0], A[1]}, f2{A[2], A[3]}};
#pragma unroll
        for (int tt = 0; tt < 2; ++tt) {
          f2 ax = __builtin_elementwise_fma(ux, smv[tt], fdx2);
          f2 ay = __builtin_elementwise_fma(vy, smv[tt], fdy2);
          f2 tx, ty;
          tx[0] = __builtin_amdgcn_fmed3f(1.0f - fabsf(ax[0]), 0.f, 1.f);
          tx[1] = __builtin_amdgcn_fmed3f(1.0f - fabsf(ax[1]), 0.f, 1.f);
          ty[0] = __builtin_amdgcn_fmed3f(1.0f - fabsf(ay[0]), 0.f, 1.f);
          ty[1] = __builtin_amdgcn_fmed3f(1.0f - fabsf(ay[1]), 0.f, 1.f);
          acc2[tt] = __builtin_elementwise_fma(tx * ty, vals[tt], acc2[tt]);
        }
      }
    }
    __syncthreads();                  // LDS reused by next batch
  }

  // add overflow (event) contributions for this thread's pixel/channels
  const int oip = (qy + 1) * OVW + (qx + 1);
#pragma unroll
  for (int tt = 0; tt < 2; ++tt) {
    acc2[tt] += f2{ovf[(2 * (tb + tt)) * OVA + oip],
                   ovf[(2 * (tb + tt) + 1) * OVA + oip]};
  }

  // variance partials over this thread's 4 output cells
  double ls = 0.0, lq = 0.0;
#pragma unroll
  for (int tt = 0; tt < 2; ++tt) {
    double a = (double)acc2[tt].x, b2 = (double)acc2[tt].y;
    ls += a + b2;
    lq += a * a + b2 * b2;
  }
  for (int off = 32; off > 0; off >>= 1) {
    ls += __shfl_down(ls, off, 64);
    lq += __shfl_down(lq, off, 64);
  }
  if ((tid & 63) == 0) { red[wave * 2] = ls; red[wave * 2 + 1] = lq; }
  __syncthreads();
  if (tid == 0) {
    partials[2 * bid] = red[0] + red[2] + red[4] + red[6];
    partials[2 * bid + 1] = red[1] + red[3] + red[5] + red[7];
  }
}

// ---------------------------------------------------------------------------
// Finalize: reduce NBLK partial pairs, loss = -(sumsq - sum^2/N)/(N-1)
// ---------------------------------------------------------------------------
__global__ __launch_bounds__(256) void finalize_kernel(
    const double* __restrict__ partials, float* __restrict__ out) {
  double s = 0.0, q = 0.0;
  for (int i = threadIdx.x; i < NBLK; i += 256) {
    s += partials[2 * i];
    q += partials[2 * i + 1];
  }
  for (int off = 32; off > 0; off >>= 1) {
    s += __shfl_down(s, off, 64);
    q += __shfl_down(q, off, 64);
  }
  __shared__ double ss[4], qq[4];
  int lane = threadIdx.x & 63;
  int wave = threadIdx.x >> 6;
  if (lane == 0) { ss[wave] = s; qq[wave] = q; }
  __syncthreads();
  if (threadIdx.x == 0) {
    double sum = ss[0] + ss[1] + ss[2] + ss[3];
    double sq = qq[0] + qq[1] + qq[2] + qq[3];
    double n = (double)N_TOT;
    double var = (sq - sum * sum / n) / (n - 1.0);
    out[0] = (float)(-var);
  }
}

extern "C" void kernel_launch(void* const* d_in, const int* in_sizes, int n_in,
                              void* d_out, int out_size, void* d_ws, size_t ws_size,
                              hipStream_t stream) {
  const float* flow = (const float*)d_in[0];
  const float* spike = (const float*)d_in[1];
  float* out = (float*)d_out;
  double* partials = (double*)d_ws;   // 2*NBLK doubles, fully written each call

  fused_kernel<<<dim3(NBLK), dim3(256), 0, stream>>>(flow, spike, partials);
  finalize_kernel<<<1, dim3(256), 0, stream>>>(partials, out);
}